// Round 2
// baseline (702.926 us; speedup 1.0000x reference)
//
#include <hip/hip_runtime.h>

#define N_NODES 100000
#define N_EDGES 3200000
#define D_FEAT  512
#define HIDDEN  16
#define NCLS    6

// ---------- helpers ----------

// edge_index may arrive as int32 (JAX x64 disabled) or int64 (x64 enabled).
// flag==1 means int64 layout (pairs of i32, low word first, little-endian).
__device__ __forceinline__ int eidx(const int* __restrict__ ei, int is64, int pos) {
    return is64 ? ei[2 * (long long)pos] : ei[pos];
}

__global__ void k_detect(const int* __restrict__ ei, int* __restrict__ flag) {
    int v = ei[2 * threadIdx.x + 1];
    unsigned long long b = __ballot(v != 0);
    if (threadIdx.x == 0) flag[0] = (b == 0ULL) ? 1 : 0;
}

// ---------- CSR build (by destination col) ----------

__global__ void k_hist(const int* __restrict__ ei, const int* __restrict__ flag,
                       int* __restrict__ counts) {
    int e = blockIdx.x * 256 + threadIdx.x;
    if (e >= N_EDGES) return;
    int c = eidx(ei, flag[0], N_EDGES + e);
    atomicAdd(&counts[c], 1);
}

// exclusive scan, phase A: per-block scan of 256 counts
__global__ void k_scanA(const int* __restrict__ counts, int* __restrict__ excl,
                        int* __restrict__ bsum) {
    __shared__ int s[256];
    int t = threadIdx.x;
    int i = blockIdx.x * 256 + t;
    int v = (i < N_NODES) ? counts[i] : 0;
    s[t] = v;
    __syncthreads();
    for (int off = 1; off < 256; off <<= 1) {
        int u = (t >= off) ? s[t - off] : 0;
        __syncthreads();
        s[t] += u;
        __syncthreads();
    }
    if (i < N_NODES) excl[i] = s[t] - v;
    if (t == 255) bsum[blockIdx.x] = s[255];
}

// phase B: scan of block sums (nb <= 512), in place, exclusive
__global__ void k_scanB(int* __restrict__ bsum, int nb) {
    __shared__ int s[512];
    int t = threadIdx.x;
    int v = (t < nb) ? bsum[t] : 0;
    s[t] = v;
    __syncthreads();
    for (int off = 1; off < 512; off <<= 1) {
        int u = (t >= off) ? s[t - off] : 0;
        __syncthreads();
        s[t] += u;
        __syncthreads();
    }
    if (t < nb) bsum[t] = s[t] - v;
}

// phase C: add block offsets
__global__ void k_scanC(int* __restrict__ excl, const int* __restrict__ bsum) {
    int i = blockIdx.x * 256 + threadIdx.x;
    if (i < N_NODES) excl[i] += bsum[blockIdx.x];
}

__global__ void k_fill(const int* __restrict__ ei, const float* __restrict__ ew,
                       const int* __restrict__ flag, const int* __restrict__ start,
                       int* __restrict__ cursor, int* __restrict__ rperm,
                       float* __restrict__ wperm) {
    int e = blockIdx.x * 256 + threadIdx.x;
    if (e >= N_EDGES) return;
    int is64 = flag[0];
    int r = eidx(ei, is64, e);
    int c = eidx(ei, is64, N_EDGES + e);
    int p = start[c] + atomicAdd(&cursor[c], 1);
    rperm[p] = r;
    wperm[p] = ew[e];
}

// deg[i] = 1 + sum of incoming w; store dinv in place
__global__ void k_deg(const int* __restrict__ start, const int* __restrict__ counts,
                      const float* __restrict__ wperm, float* __restrict__ deg) {
    int i = blockIdx.x * 256 + threadIdx.x;
    if (i >= N_NODES) return;
    int s0 = start[i], n = counts[i];
    float s = 1.0f;
    for (int k = 0; k < n; ++k) s += wperm[s0 + k];
    deg[i] = (s > 0.0f) ? rsqrtf(s) : 0.0f;
}

// wperm[e] *= dinv[rperm[e]]  (so gathers only need dinv[col], hoisted)
__global__ void k_wd(const int* __restrict__ rperm, const float* __restrict__ dinv,
                     float* __restrict__ wperm) {
    int e = blockIdx.x * 256 + threadIdx.x;
    if (e >= N_EDGES) return;
    wperm[e] *= dinv[rperm[e]];
}

// ---------- layer 1 transform: h1 = x @ W1 ----------

__global__ __launch_bounds__(256)
void k_gemm1(const float* __restrict__ x, const float* __restrict__ W1g,
             float* __restrict__ h1) {
    __shared__ float w1s[D_FEAT * HIDDEN];   // 32 KB
    for (int p = threadIdx.x; p < D_FEAT * HIDDEN; p += 256) w1s[p] = W1g[p];
    __syncthreads();
    const int total = N_NODES * HIDDEN;
    for (int t = blockIdx.x * 256 + threadIdx.x; t < total; t += gridDim.x * 256) {
        int i = t >> 4, j = t & 15;
        const float4* xr = (const float4*)(x + (size_t)i * D_FEAT);
        float acc = 0.0f;
#pragma unroll 4
        for (int k4 = 0; k4 < D_FEAT / 4; ++k4) {
            float4 xv = xr[k4];
            int kb = (k4 << 6) + j;
            acc = fmaf(xv.x, w1s[kb],      acc);
            acc = fmaf(xv.y, w1s[kb + 16], acc);
            acc = fmaf(xv.z, w1s[kb + 32], acc);
            acc = fmaf(xv.w, w1s[kb + 48], acc);
        }
        h1[t] = acc;
    }
}

// ---------- gather layer 1 (+ bias + self-loop) fused with gemm2 ----------

__global__ __launch_bounds__(256)
void k_gather1(const int* __restrict__ start, const int* __restrict__ counts,
               const int* __restrict__ rperm, const float* __restrict__ wperm,
               const float* __restrict__ dinv, const float* __restrict__ h1,
               const float* __restrict__ b1, const float* __restrict__ W2g,
               float* __restrict__ x1, float* __restrict__ h2) {
    __shared__ float sW2[HIDDEN * NCLS];
    __shared__ float sv[16][HIDDEN + 1];
    if (threadIdx.x < HIDDEN * NCLS) sW2[threadIdx.x] = W2g[threadIdx.x];
    int ln = threadIdx.x >> 4, j = threadIdx.x & 15;
    int i = blockIdx.x * 16 + ln;
    bool act = (i < N_NODES);
    float v = 0.0f;
    if (act) {
        int s0 = start[i], n = counts[i];
        float acc = 0.0f;
        for (int k = 0; k < n; ++k) {
            int r = rperm[s0 + k];
            acc += wperm[s0 + k] * h1[(size_t)r * HIDDEN + j];
        }
        float di = dinv[i];
        v = di * acc + di * di * h1[(size_t)i * HIDDEN + j] + b1[j];
        x1[(size_t)i * HIDDEN + j] = v;
    }
    sv[ln][j] = v;
    __syncthreads();
    if (act && j < NCLS) {
        float a = 0.0f;
#pragma unroll
        for (int k = 0; k < HIDDEN; ++k) a = fmaf(sv[ln][k], sW2[k * NCLS + j], a);
        h2[(size_t)i * NCLS + j] = a;
    }
}

// ---------- gather layer 2 fused with log_softmax ----------

__global__ __launch_bounds__(256)
void k_gather2(const int* __restrict__ start, const int* __restrict__ counts,
               const int* __restrict__ rperm, const float* __restrict__ wperm,
               const float* __restrict__ dinv, const float* __restrict__ h2,
               const float* __restrict__ b2, float* __restrict__ out) {
    __shared__ float sv[32][8];
    int ln = threadIdx.x >> 3, j = threadIdx.x & 7;
    int i = blockIdx.x * 32 + ln;
    bool act = (i < N_NODES) && (j < NCLS);
    float v = 0.0f;
    if (act) {
        int s0 = start[i], n = counts[i];
        float acc = 0.0f;
        for (int k = 0; k < n; ++k) {
            int r = rperm[s0 + k];
            acc += wperm[s0 + k] * h2[(size_t)r * NCLS + j];
        }
        float di = dinv[i];
        v = di * acc + di * di * h2[(size_t)i * NCLS + j] + b2[j];
    }
    sv[ln][j] = v;
    __syncthreads();
    if (act) {
        float m = -1e30f;
#pragma unroll
        for (int k = 0; k < NCLS; ++k) m = fmaxf(m, sv[ln][k]);
        float s = 0.0f;
#pragma unroll
        for (int k = 0; k < NCLS; ++k) s += __expf(sv[ln][k] - m);
        out[(size_t)i * NCLS + j] = v - m - __logf(s);
    }
}

// ---------- fallback (atomic) path kernels, used when ws_size is small ----------

__global__ void k_initdeg(float* __restrict__ deg) {
    int i = blockIdx.x * 256 + threadIdx.x;
    if (i < N_NODES) deg[i] = 1.0f;
}

__global__ void k_degacc(const int* __restrict__ ei, const float* __restrict__ w,
                         const int* __restrict__ flag, float* __restrict__ deg) {
    int e = blockIdx.x * 256 + threadIdx.x;
    if (e >= N_EDGES) return;
    int c = eidx(ei, flag[0], N_EDGES + e);
    atomicAdd(&deg[c], w[e]);
}

__global__ void k_dinv(float* __restrict__ deg) {
    int i = blockIdx.x * 256 + threadIdx.x;
    if (i < N_NODES) {
        float d = deg[i];
        deg[i] = (d > 0.0f) ? rsqrtf(d) : 0.0f;
    }
}

__global__ __launch_bounds__(256)
void k_scatter1(const int* __restrict__ ei, const float* __restrict__ w,
                const int* __restrict__ flag, const float* __restrict__ dinv,
                const float* __restrict__ h1, float* __restrict__ agg1) {
    int t = blockIdx.x * 256 + threadIdx.x;
    if (t >= N_EDGES * HIDDEN) return;
    int e = t >> 4, j = t & 15;
    int is64 = flag[0];
    int r = eidx(ei, is64, e);
    int c = eidx(ei, is64, N_EDGES + e);
    float nrm = dinv[r] * w[e] * dinv[c];
    atomicAdd(&agg1[(size_t)c * HIDDEN + j], nrm * h1[(size_t)r * HIDDEN + j]);
}

__global__ void k_fin1_gemm2(const float* __restrict__ b1, const float* __restrict__ W2,
                             const float* __restrict__ dinv, const float* __restrict__ h1,
                             float* __restrict__ x1, float* __restrict__ h2) {
    int i = blockIdx.x * 256 + threadIdx.x;
    if (i >= N_NODES) return;
    float d2 = dinv[i] * dinv[i];
    float v[HIDDEN];
#pragma unroll
    for (int k = 0; k < HIDDEN; ++k)
        v[k] = x1[(size_t)i * HIDDEN + k] + d2 * h1[(size_t)i * HIDDEN + k] + b1[k];
#pragma unroll
    for (int k = 0; k < HIDDEN; ++k)
        x1[(size_t)i * HIDDEN + k] = v[k];
#pragma unroll
    for (int j = 0; j < NCLS; ++j) {
        float a = 0.0f;
#pragma unroll
        for (int k = 0; k < HIDDEN; ++k) a = fmaf(v[k], W2[k * NCLS + j], a);
        h2[(size_t)i * NCLS + j] = a;
    }
}

__global__ __launch_bounds__(256)
void k_scatter2(const int* __restrict__ ei, const float* __restrict__ w,
                const int* __restrict__ flag, const float* __restrict__ dinv,
                const float* __restrict__ h2, float* __restrict__ agg2) {
    int t = blockIdx.x * 256 + threadIdx.x;
    if (t >= N_EDGES * NCLS) return;
    int e = t / NCLS, j = t - e * NCLS;
    int is64 = flag[0];
    int r = eidx(ei, is64, e);
    int c = eidx(ei, is64, N_EDGES + e);
    float nrm = dinv[r] * w[e] * dinv[c];
    atomicAdd(&agg2[(size_t)c * NCLS + j], nrm * h2[(size_t)r * NCLS + j]);
}

__global__ void k_final(const float* __restrict__ agg2, const float* __restrict__ h2,
                        const float* __restrict__ dinv, const float* __restrict__ b2,
                        float* __restrict__ out) {
    int i = blockIdx.x * 256 + threadIdx.x;
    if (i >= N_NODES) return;
    float d2 = dinv[i] * dinv[i];
    float v[NCLS];
    float m = -1e30f;
#pragma unroll
    for (int j = 0; j < NCLS; ++j) {
        v[j] = agg2[(size_t)i * NCLS + j] + d2 * h2[(size_t)i * NCLS + j] + b2[j];
        m = fmaxf(m, v[j]);
    }
    float s = 0.0f;
#pragma unroll
    for (int j = 0; j < NCLS; ++j) s += __expf(v[j] - m);
    float l = __logf(s);
#pragma unroll
    for (int j = 0; j < NCLS; ++j) out[(size_t)i * NCLS + j] = v[j] - m - l;
}

// ---------- launch ----------

extern "C" void kernel_launch(void* const* d_in, const int* in_sizes, int n_in,
                              void* d_out, int out_size, void* d_ws, size_t ws_size,
                              hipStream_t stream) {
    const float* x  = (const float*)d_in[0];
    const float* W1 = (const float*)d_in[1];
    const float* b1 = (const float*)d_in[2];
    const float* W2 = (const float*)d_in[3];
    const float* b2 = (const float*)d_in[4];
    const float* ew = (const float*)d_in[5];
    const int*   ei = (const int*)d_in[6];

    float* out = (float*)d_out;
    float* lsm = out;                               // [N, 6]
    float* x1  = out + (size_t)N_NODES * NCLS;      // [N, 16]

    const int NB_N = (N_NODES + 255) / 256;         // 391
    const int NB_E = (N_EDGES + 255) / 256;

    float* W    = (float*)d_ws;
    int*   flag = (int*)d_ws;

    // ---- CSR (gather) path layout, 4B units ----
    float* deg    = W + 1024;            // 100000  (becomes dinv)
    int*   counts = (int*)(W + 102400);  // 100000
    int*   startA = (int*)(W + 203776);  // 100001
    int*   cursor = (int*)(W + 304128);  // 100000
    int*   bsum   = (int*)(W + 405504);  // 512
    float* h1     = W + 406528;          // 1,600,000
    float* h2     = W + 2007040;         // 600,000
    int*   rperm  = (int*)(W + 2607616); // 3,200,000
    float* wperm  = W + 5808128;         // 3,200,000
    const size_t NEED = (size_t)9008128 * 4;        // ~36 MB

    if (ws_size >= NEED) {
        hipMemsetAsync(counts, 0, (size_t)N_NODES * 4, stream);
        hipMemsetAsync(cursor, 0, (size_t)N_NODES * 4, stream);
        k_detect<<<1, 64, 0, stream>>>(ei, flag);
        k_hist  <<<NB_E, 256, 0, stream>>>(ei, flag, counts);
        k_scanA <<<NB_N, 256, 0, stream>>>(counts, startA, bsum);
        k_scanB <<<1, 512, 0, stream>>>(bsum, NB_N);
        k_scanC <<<NB_N, 256, 0, stream>>>(startA, bsum);
        k_fill  <<<NB_E, 256, 0, stream>>>(ei, ew, flag, startA, cursor, rperm, wperm);
        k_deg   <<<NB_N, 256, 0, stream>>>(startA, counts, wperm, deg);
        k_wd    <<<NB_E, 256, 0, stream>>>(rperm, deg, wperm);
        k_gemm1 <<<2048, 256, 0, stream>>>(x, W1, h1);
        k_gather1<<<(N_NODES + 15) / 16, 256, 0, stream>>>(startA, counts, rperm, wperm,
                                                           deg, h1, b1, W2, x1, h2);
        k_gather2<<<(N_NODES + 31) / 32, 256, 0, stream>>>(startA, counts, rperm, wperm,
                                                           deg, h2, b2, lsm);
    } else {
        // ---- fallback: atomic scatter path (ws ~11.6 MB) ----
        float* fh1  = W + 101376;
        float* fh2  = fh1 + (size_t)N_NODES * HIDDEN;
        float* agg2 = fh2 + (size_t)N_NODES * NCLS;
        hipMemsetAsync(x1,   0, (size_t)N_NODES * HIDDEN * sizeof(float), stream);
        hipMemsetAsync(agg2, 0, (size_t)N_NODES * NCLS   * sizeof(float), stream);
        k_detect <<<1, 64, 0, stream>>>(ei, flag);
        k_initdeg<<<NB_N, 256, 0, stream>>>(deg);
        k_degacc <<<NB_E, 256, 0, stream>>>(ei, ew, flag, deg);
        k_dinv   <<<NB_N, 256, 0, stream>>>(deg);
        k_gemm1  <<<2048, 256, 0, stream>>>(x, W1, fh1);
        k_scatter1<<<(N_EDGES * HIDDEN + 255) / 256, 256, 0, stream>>>(ei, ew, flag, deg, fh1, x1);
        k_fin1_gemm2<<<NB_N, 256, 0, stream>>>(b1, W2, deg, fh1, x1, fh2);
        k_scatter2<<<(N_EDGES * NCLS + 255) / 256, 256, 0, stream>>>(ei, ew, flag, deg, fh2, agg2);
        k_final  <<<NB_N, 256, 0, stream>>>(agg2, fh2, deg, b2, lsm);
    }
}

// Round 3
// 456.268 us; speedup vs baseline: 1.5406x; 1.5406x over previous
//
#include <hip/hip_runtime.h>

#define N_NODES 100000
#define N_EDGES 3200000
#define D_FEAT  512
#define HIDDEN  16
#define NCLS    6
#define NBUK    391          // ceil(N_NODES/256), bucket = col>>8
#define TILE    8192
#define NBLK_A  391          // ceil(N_EDGES/TILE)

// ---------- helpers ----------

// edge_index may arrive as int32 (JAX x64 disabled) or int64 (x64 enabled).
// flag==1 means int64 layout (pairs of i32, low word first, little-endian).
__device__ __forceinline__ int eidx(const int* __restrict__ ei, int is64, int pos) {
    return is64 ? ei[2 * (long long)pos] : ei[pos];
}

__global__ void k_detect(const int* __restrict__ ei, int* __restrict__ flag) {
    int v = ei[2 * threadIdx.x + 1];
    unsigned long long b = __ballot(v != 0);
    if (threadIdx.x == 0) flag[0] = (b == 0ULL) ? 1 : 0;
}

// ---------- radix CSR build: pass A0 — bucket histogram ----------

__global__ __launch_bounds__(256)
void k_bhist(const int* __restrict__ ei, const int* __restrict__ flag,
             int* __restrict__ bcnt) {
    __shared__ int lh[NBUK];
    for (int i = threadIdx.x; i < NBUK; i += 256) lh[i] = 0;
    __syncthreads();
    int is64 = flag[0];
    int s = blockIdx.x * TILE, e1 = min(s + TILE, N_EDGES);
    for (int e = s + threadIdx.x; e < e1; e += 256) {
        int c = eidx(ei, is64, N_EDGES + e);
        atomicAdd(&lh[c >> 8], 1);
    }
    __syncthreads();
    for (int i = threadIdx.x; i < NBUK; i += 256)
        if (lh[i]) atomicAdd(&bcnt[i], lh[i]);
}

// scan of NBUK bucket counts -> bstart (excl, +total at [NBUK]) and bcursor
__global__ void k_bscan(const int* __restrict__ bcnt, int* __restrict__ bstart,
                        int* __restrict__ bcursor) {
    __shared__ int s[512];
    int t = threadIdx.x;
    int v = (t < NBUK) ? bcnt[t] : 0;
    s[t] = v;
    __syncthreads();
    for (int off = 1; off < 512; off <<= 1) {
        int u = (t >= off) ? s[t - off] : 0;
        __syncthreads();
        s[t] += u;
        __syncthreads();
    }
    int excl = s[t] - v;
    if (t <= NBUK) bstart[t] = excl;
    if (t < NBUK)  bcursor[t] = excl;
}

// pass A1: scatter edges into bucket-major abuf with block-reserved runs
__global__ __launch_bounds__(256)
void k_bscat(const int* __restrict__ ei, const float* __restrict__ ew,
             const int* __restrict__ flag, int* __restrict__ bcursor,
             uint2* __restrict__ abuf) {
    __shared__ int lh[NBUK];
    __shared__ int lbase[NBUK];
    __shared__ int lcur[NBUK];
    for (int i = threadIdx.x; i < NBUK; i += 256) { lh[i] = 0; lcur[i] = 0; }
    __syncthreads();
    int is64 = flag[0];
    int s = blockIdx.x * TILE, e1 = min(s + TILE, N_EDGES);
    for (int e = s + threadIdx.x; e < e1; e += 256) {
        int c = eidx(ei, is64, N_EDGES + e);
        atomicAdd(&lh[c >> 8], 1);
    }
    __syncthreads();
    for (int i = threadIdx.x; i < NBUK; i += 256)
        if (lh[i]) lbase[i] = atomicAdd(&bcursor[i], lh[i]);
    __syncthreads();
    for (int e = s + threadIdx.x; e < e1; e += 256) {
        int r = eidx(ei, is64, e);
        int c = eidx(ei, is64, N_EDGES + e);
        float w = ew[e];
        int b = c >> 8;
        int off = atomicAdd(&lcur[b], 1);
        int p = lbase[b] + off;
        abuf[p] = make_uint2((unsigned)r | ((unsigned)(c & 255) << 17),
                             __float_as_uint(w));
    }
}

// pass B: per-bucket counting sort into final CSR; emits start/counts/dinv
__global__ __launch_bounds__(256)
void k_bsort(const int* __restrict__ bstart, const uint2* __restrict__ abuf,
             int* __restrict__ rperm, float* __restrict__ wperm,
             int* __restrict__ startA, int* __restrict__ counts,
             float* __restrict__ dinv) {
    __shared__ int   cnt[256];
    __shared__ int   scn[256];
    __shared__ int   cur[256];
    __shared__ float wsum[256];
    int t = threadIdx.x;
    int b = blockIdx.x;
    int s0 = bstart[b], s1 = bstart[b + 1];
    cnt[t] = 0; wsum[t] = 0.0f;
    __syncthreads();
    for (int k = s0 + t; k < s1; k += 256) {
        int ln = (int)(abuf[k].x >> 17);
        atomicAdd(&cnt[ln], 1);
    }
    __syncthreads();
    scn[t] = cnt[t];
    __syncthreads();
    for (int off = 1; off < 256; off <<= 1) {
        int u = (t >= off) ? scn[t - off] : 0;
        __syncthreads();
        scn[t] += u;
        __syncthreads();
    }
    int excl = scn[t] - cnt[t];
    cur[t] = excl;
    int node = b * 256 + t;
    if (node < N_NODES) {
        startA[node] = s0 + excl;
        counts[node] = cnt[t];
    }
    __syncthreads();
    for (int k = s0 + t; k < s1; k += 256) {
        uint2 a = abuf[k];
        int ln = (int)(a.x >> 17);
        int r  = (int)(a.x & 0x1FFFFu);
        float w = __uint_as_float(a.y);
        int off = atomicAdd(&cur[ln], 1);
        int p = s0 + off;
        rperm[p] = r;
        wperm[p] = w;
        atomicAdd(&wsum[ln], w);
    }
    __syncthreads();
    if (node < N_NODES) dinv[node] = rsqrtf(1.0f + wsum[t]);   // deg >= 1 (self-loop)
}

// ---------- layer 1 transform: h1 = x @ W1 ----------

__global__ __launch_bounds__(256)
void k_gemm1(const float* __restrict__ x, const float* __restrict__ W1g,
             float* __restrict__ h1) {
    __shared__ float w1s[D_FEAT * HIDDEN];   // 32 KB
    for (int p = threadIdx.x; p < D_FEAT * HIDDEN; p += 256) w1s[p] = W1g[p];
    __syncthreads();
    const int total = N_NODES * HIDDEN;
    for (int t = blockIdx.x * 256 + threadIdx.x; t < total; t += gridDim.x * 256) {
        int i = t >> 4, j = t & 15;
        const float4* xr = (const float4*)(x + (size_t)i * D_FEAT);
        float acc = 0.0f;
#pragma unroll 4
        for (int k4 = 0; k4 < D_FEAT / 4; ++k4) {
            float4 xv = xr[k4];
            int kb = (k4 << 6) + j;
            acc = fmaf(xv.x, w1s[kb],      acc);
            acc = fmaf(xv.y, w1s[kb + 16], acc);
            acc = fmaf(xv.z, w1s[kb + 32], acc);
            acc = fmaf(xv.w, w1s[kb + 48], acc);
        }
        h1[t] = acc;
    }
}

// ---------- gather layer 1 (+ bias + self-loop) fused with gemm2 ----------
// wperm holds raw w; dinv[row] applied inline (L1-resident 400KB table).

__global__ __launch_bounds__(256)
void k_gather1(const int* __restrict__ start, const int* __restrict__ counts,
               const int* __restrict__ rperm, const float* __restrict__ wperm,
               const float* __restrict__ dinv, const float* __restrict__ h1,
               const float* __restrict__ b1, const float* __restrict__ W2g,
               float* __restrict__ x1, float* __restrict__ h2) {
    __shared__ float sW2[HIDDEN * NCLS];
    __shared__ float sv[16][HIDDEN + 1];
    if (threadIdx.x < HIDDEN * NCLS) sW2[threadIdx.x] = W2g[threadIdx.x];
    int ln = threadIdx.x >> 4, j = threadIdx.x & 15;
    int i = blockIdx.x * 16 + ln;
    bool act = (i < N_NODES);
    float v = 0.0f;
    if (act) {
        int s0 = start[i], n = counts[i];
        float acc = 0.0f;
        for (int k = 0; k < n; ++k) {
            int r = rperm[s0 + k];
            acc += wperm[s0 + k] * dinv[r] * h1[(size_t)r * HIDDEN + j];
        }
        float di = dinv[i];
        v = di * acc + di * di * h1[(size_t)i * HIDDEN + j] + b1[j];
        x1[(size_t)i * HIDDEN + j] = v;
    }
    sv[ln][j] = v;
    __syncthreads();
    if (act && j < NCLS) {
        float a = 0.0f;
#pragma unroll
        for (int k = 0; k < HIDDEN; ++k) a = fmaf(sv[ln][k], sW2[k * NCLS + j], a);
        h2[(size_t)i * NCLS + j] = a;
    }
}

// ---------- gather layer 2 fused with log_softmax ----------

__global__ __launch_bounds__(256)
void k_gather2(const int* __restrict__ start, const int* __restrict__ counts,
               const int* __restrict__ rperm, const float* __restrict__ wperm,
               const float* __restrict__ dinv, const float* __restrict__ h2,
               const float* __restrict__ b2, float* __restrict__ out) {
    __shared__ float sv[32][8];
    int ln = threadIdx.x >> 3, j = threadIdx.x & 7;
    int i = blockIdx.x * 32 + ln;
    bool act = (i < N_NODES) && (j < NCLS);
    float v = 0.0f;
    if (act) {
        int s0 = start[i], n = counts[i];
        float acc = 0.0f;
        for (int k = 0; k < n; ++k) {
            int r = rperm[s0 + k];
            acc += wperm[s0 + k] * dinv[r] * h2[(size_t)r * NCLS + j];
        }
        float di = dinv[i];
        v = di * acc + di * di * h2[(size_t)i * NCLS + j] + b2[j];
    }
    sv[ln][j] = v;
    __syncthreads();
    if (act) {
        float m = -1e30f;
#pragma unroll
        for (int k = 0; k < NCLS; ++k) m = fmaxf(m, sv[ln][k]);
        float s = 0.0f;
#pragma unroll
        for (int k = 0; k < NCLS; ++k) s += __expf(sv[ln][k] - m);
        out[(size_t)i * NCLS + j] = v - m - __logf(s);
    }
}

// ---------- tier-2 CSR build kernels (R2 path, proven) ----------

__global__ void k_hist(const int* __restrict__ ei, const int* __restrict__ flag,
                       int* __restrict__ counts) {
    int e = blockIdx.x * 256 + threadIdx.x;
    if (e >= N_EDGES) return;
    int c = eidx(ei, flag[0], N_EDGES + e);
    atomicAdd(&counts[c], 1);
}

__global__ void k_scanA(const int* __restrict__ counts, int* __restrict__ excl,
                        int* __restrict__ bsum) {
    __shared__ int s[256];
    int t = threadIdx.x;
    int i = blockIdx.x * 256 + t;
    int v = (i < N_NODES) ? counts[i] : 0;
    s[t] = v;
    __syncthreads();
    for (int off = 1; off < 256; off <<= 1) {
        int u = (t >= off) ? s[t - off] : 0;
        __syncthreads();
        s[t] += u;
        __syncthreads();
    }
    if (i < N_NODES) excl[i] = s[t] - v;
    if (t == 255) bsum[blockIdx.x] = s[255];
}

__global__ void k_scanB(int* __restrict__ bsum, int nb) {
    __shared__ int s[512];
    int t = threadIdx.x;
    int v = (t < nb) ? bsum[t] : 0;
    s[t] = v;
    __syncthreads();
    for (int off = 1; off < 512; off <<= 1) {
        int u = (t >= off) ? s[t - off] : 0;
        __syncthreads();
        s[t] += u;
        __syncthreads();
    }
    if (t < nb) bsum[t] = s[t] - v;
}

__global__ void k_scanC(int* __restrict__ excl, const int* __restrict__ bsum) {
    int i = blockIdx.x * 256 + threadIdx.x;
    if (i < N_NODES) excl[i] += bsum[blockIdx.x];
}

__global__ void k_fill(const int* __restrict__ ei, const float* __restrict__ ew,
                       const int* __restrict__ flag, const int* __restrict__ start,
                       int* __restrict__ cursor, int* __restrict__ rperm,
                       float* __restrict__ wperm) {
    int e = blockIdx.x * 256 + threadIdx.x;
    if (e >= N_EDGES) return;
    int is64 = flag[0];
    int r = eidx(ei, is64, e);
    int c = eidx(ei, is64, N_EDGES + e);
    int p = start[c] + atomicAdd(&cursor[c], 1);
    rperm[p] = r;
    wperm[p] = ew[e];
}

__global__ void k_deg(const int* __restrict__ start, const int* __restrict__ counts,
                      const float* __restrict__ wperm, float* __restrict__ deg) {
    int i = blockIdx.x * 256 + threadIdx.x;
    if (i >= N_NODES) return;
    int s0 = start[i], n = counts[i];
    float s = 1.0f;
    for (int k = 0; k < n; ++k) s += wperm[s0 + k];
    deg[i] = rsqrtf(s);
}

// ---------- tier-3 atomic fallback kernels ----------

__global__ void k_initdeg(float* __restrict__ deg) {
    int i = blockIdx.x * 256 + threadIdx.x;
    if (i < N_NODES) deg[i] = 1.0f;
}

__global__ void k_degacc(const int* __restrict__ ei, const float* __restrict__ w,
                         const int* __restrict__ flag, float* __restrict__ deg) {
    int e = blockIdx.x * 256 + threadIdx.x;
    if (e >= N_EDGES) return;
    int c = eidx(ei, flag[0], N_EDGES + e);
    atomicAdd(&deg[c], w[e]);
}

__global__ void k_dinv(float* __restrict__ deg) {
    int i = blockIdx.x * 256 + threadIdx.x;
    if (i < N_NODES) {
        float d = deg[i];
        deg[i] = (d > 0.0f) ? rsqrtf(d) : 0.0f;
    }
}

__global__ __launch_bounds__(256)
void k_scatter1(const int* __restrict__ ei, const float* __restrict__ w,
                const int* __restrict__ flag, const float* __restrict__ dinv,
                const float* __restrict__ h1, float* __restrict__ agg1) {
    int t = blockIdx.x * 256 + threadIdx.x;
    if (t >= N_EDGES * HIDDEN) return;
    int e = t >> 4, j = t & 15;
    int is64 = flag[0];
    int r = eidx(ei, is64, e);
    int c = eidx(ei, is64, N_EDGES + e);
    float nrm = dinv[r] * w[e] * dinv[c];
    atomicAdd(&agg1[(size_t)c * HIDDEN + j], nrm * h1[(size_t)r * HIDDEN + j]);
}

__global__ void k_fin1_gemm2(const float* __restrict__ b1, const float* __restrict__ W2,
                             const float* __restrict__ dinv, const float* __restrict__ h1,
                             float* __restrict__ x1, float* __restrict__ h2) {
    int i = blockIdx.x * 256 + threadIdx.x;
    if (i >= N_NODES) return;
    float d2 = dinv[i] * dinv[i];
    float v[HIDDEN];
#pragma unroll
    for (int k = 0; k < HIDDEN; ++k)
        v[k] = x1[(size_t)i * HIDDEN + k] + d2 * h1[(size_t)i * HIDDEN + k] + b1[k];
#pragma unroll
    for (int k = 0; k < HIDDEN; ++k)
        x1[(size_t)i * HIDDEN + k] = v[k];
#pragma unroll
    for (int j = 0; j < NCLS; ++j) {
        float a = 0.0f;
#pragma unroll
        for (int k = 0; k < HIDDEN; ++k) a = fmaf(v[k], W2[k * NCLS + j], a);
        h2[(size_t)i * NCLS + j] = a;
    }
}

__global__ __launch_bounds__(256)
void k_scatter2(const int* __restrict__ ei, const float* __restrict__ w,
                const int* __restrict__ flag, const float* __restrict__ dinv,
                const float* __restrict__ h2, float* __restrict__ agg2) {
    int t = blockIdx.x * 256 + threadIdx.x;
    if (t >= N_EDGES * NCLS) return;
    int e = t / NCLS, j = t - e * NCLS;
    int is64 = flag[0];
    int r = eidx(ei, is64, e);
    int c = eidx(ei, is64, N_EDGES + e);
    float nrm = dinv[r] * w[e] * dinv[c];
    atomicAdd(&agg2[(size_t)c * NCLS + j], nrm * h2[(size_t)r * NCLS + j]);
}

__global__ void k_final(const float* __restrict__ agg2, const float* __restrict__ h2,
                        const float* __restrict__ dinv, const float* __restrict__ b2,
                        float* __restrict__ out) {
    int i = blockIdx.x * 256 + threadIdx.x;
    if (i >= N_NODES) return;
    float d2 = dinv[i] * dinv[i];
    float v[NCLS];
    float m = -1e30f;
#pragma unroll
    for (int j = 0; j < NCLS; ++j) {
        v[j] = agg2[(size_t)i * NCLS + j] + d2 * h2[(size_t)i * NCLS + j] + b2[j];
        m = fmaxf(m, v[j]);
    }
    float s = 0.0f;
#pragma unroll
    for (int j = 0; j < NCLS; ++j) s += __expf(v[j] - m);
    float l = __logf(s);
#pragma unroll
    for (int j = 0; j < NCLS; ++j) out[(size_t)i * NCLS + j] = v[j] - m - l;
}

// ---------- launch ----------

extern "C" void kernel_launch(void* const* d_in, const int* in_sizes, int n_in,
                              void* d_out, int out_size, void* d_ws, size_t ws_size,
                              hipStream_t stream) {
    const float* x  = (const float*)d_in[0];
    const float* W1 = (const float*)d_in[1];
    const float* b1 = (const float*)d_in[2];
    const float* W2 = (const float*)d_in[3];
    const float* b2 = (const float*)d_in[4];
    const float* ew = (const float*)d_in[5];
    const int*   ei = (const int*)d_in[6];

    float* out = (float*)d_out;
    float* lsm = out;                               // [N, 6]
    float* x1  = out + (size_t)N_NODES * NCLS;      // [N, 16]

    const int NB_N = (N_NODES + 255) / 256;         // 391
    const int NB_E = (N_EDGES + 255) / 256;

    float* W    = (float*)d_ws;
    int*   flag = (int*)d_ws;

    // ---- tier-1 radix layout (4B words) ----
    int*   bcnt    = (int*)(W + 256);        // 392
    int*   bstart  = (int*)(W + 768);        // 392
    int*   bcursor = (int*)(W + 1280);       // 391
    int*   countsR = (int*)(W + 1792);       // 100000
    int*   startR  = (int*)(W + 102400);     // 100001
    float* dinvR   = W + 202496;             // 100000
    uint2* abuf    = (uint2*)(W + 302848);   // 3.2M uint2 (25.6MB), aliased with:
    float* h1R     = W + 302848;             //   1.6M (written after abuf dies)
    float* h2R     = W + 1902848;            //   600K
    int*   rpermR  = (int*)(W + 6702848);    // 3.2M
    float* wpermR  = W + 9902848;            // 3.2M
    const size_t NEED2 = (size_t)13102848 * 4;      // ~52.4 MB

    // ---- tier-2 (R2) layout ----
    float* deg    = W + 1024;
    int*   counts = (int*)(W + 102400);
    int*   startA = (int*)(W + 203776);
    int*   cursor = (int*)(W + 304128);
    int*   bsum   = (int*)(W + 405504);
    float* h1     = W + 406528;
    float* h2     = W + 2007040;
    int*   rperm  = (int*)(W + 2607616);
    float* wperm  = W + 5808128;
    const size_t NEED1 = (size_t)9008128 * 4;       // ~36 MB

    if (ws_size >= NEED2) {
        hipMemsetAsync(bcnt, 0, 392 * 4, stream);
        k_detect<<<1, 64, 0, stream>>>(ei, flag);
        k_bhist <<<NBLK_A, 256, 0, stream>>>(ei, flag, bcnt);
        k_bscan <<<1, 512, 0, stream>>>(bcnt, bstart, bcursor);
        k_bscat <<<NBLK_A, 256, 0, stream>>>(ei, ew, flag, bcursor, abuf);
        k_bsort <<<NBUK, 256, 0, stream>>>(bstart, abuf, rpermR, wpermR,
                                           startR, countsR, dinvR);
        k_gemm1 <<<2048, 256, 0, stream>>>(x, W1, h1R);
        k_gather1<<<(N_NODES + 15) / 16, 256, 0, stream>>>(startR, countsR, rpermR, wpermR,
                                                           dinvR, h1R, b1, W2, x1, h2R);
        k_gather2<<<(N_NODES + 31) / 32, 256, 0, stream>>>(startR, countsR, rpermR, wpermR,
                                                           dinvR, h2R, b2, lsm);
    } else if (ws_size >= NEED1) {
        hipMemsetAsync(counts, 0, (size_t)N_NODES * 4, stream);
        hipMemsetAsync(cursor, 0, (size_t)N_NODES * 4, stream);
        k_detect<<<1, 64, 0, stream>>>(ei, flag);
        k_hist  <<<NB_E, 256, 0, stream>>>(ei, flag, counts);
        k_scanA <<<NB_N, 256, 0, stream>>>(counts, startA, bsum);
        k_scanB <<<1, 512, 0, stream>>>(bsum, NB_N);
        k_scanC <<<NB_N, 256, 0, stream>>>(startA, bsum);
        k_fill  <<<NB_E, 256, 0, stream>>>(ei, ew, flag, startA, cursor, rperm, wperm);
        k_deg   <<<NB_N, 256, 0, stream>>>(startA, counts, wperm, deg);
        k_gemm1 <<<2048, 256, 0, stream>>>(x, W1, h1);
        k_gather1<<<(N_NODES + 15) / 16, 256, 0, stream>>>(startA, counts, rperm, wperm,
                                                           deg, h1, b1, W2, x1, h2);
        k_gather2<<<(N_NODES + 31) / 32, 256, 0, stream>>>(startA, counts, rperm, wperm,
                                                           deg, h2, b2, lsm);
    } else {
        float* fh1  = W + 101376;
        float* fh2  = fh1 + (size_t)N_NODES * HIDDEN;
        float* agg2 = fh2 + (size_t)N_NODES * NCLS;
        hipMemsetAsync(x1,   0, (size_t)N_NODES * HIDDEN * sizeof(float), stream);
        hipMemsetAsync(agg2, 0, (size_t)N_NODES * NCLS   * sizeof(float), stream);
        k_detect <<<1, 64, 0, stream>>>(ei, flag);
        k_initdeg<<<NB_N, 256, 0, stream>>>(deg);
        k_degacc <<<NB_E, 256, 0, stream>>>(ei, ew, flag, deg);
        k_dinv   <<<NB_N, 256, 0, stream>>>(deg);
        k_gemm1  <<<2048, 256, 0, stream>>>(x, W1, fh1);
        k_scatter1<<<(N_EDGES * HIDDEN + 255) / 256, 256, 0, stream>>>(ei, ew, flag, deg, fh1, x1);
        k_fin1_gemm2<<<NB_N, 256, 0, stream>>>(b1, W2, deg, fh1, x1, fh2);
        k_scatter2<<<(N_EDGES * NCLS + 255) / 256, 256, 0, stream>>>(ei, ew, flag, deg, fh2, agg2);
        k_final  <<<NB_N, 256, 0, stream>>>(agg2, fh2, deg, b2, lsm);
    }
}

// Round 4
// 386.014 us; speedup vs baseline: 1.8210x; 1.1820x over previous
//
#include <hip/hip_runtime.h>

#define N_NODES 100000
#define N_EDGES 3200000
#define D_FEAT  512
#define HIDDEN  16
#define NCLS    6
#define NBUK    391          // ceil(N_NODES/256), bucket = col>>8
#define TILE    8192
#define NBLK_A  391          // ceil(N_EDGES/TILE)

// ---------- helpers ----------

// edge_index may arrive as int32 (JAX x64 disabled) or int64 (x64 enabled).
// flag==1 means int64 layout (pairs of i32, low word first, little-endian).
__device__ __forceinline__ int eidx(const int* __restrict__ ei, int is64, int pos) {
    return is64 ? ei[2 * (long long)pos] : ei[pos];
}

__global__ void k_detect(const int* __restrict__ ei, int* __restrict__ flag) {
    int v = ei[2 * threadIdx.x + 1];
    unsigned long long b = __ballot(v != 0);
    if (threadIdx.x == 0) flag[0] = (b == 0ULL) ? 1 : 0;
}

// ---------- radix CSR build: pass A0 — bucket histogram ----------

__global__ __launch_bounds__(256)
void k_bhist(const int* __restrict__ ei, const int* __restrict__ flag,
             int* __restrict__ bcnt) {
    __shared__ int lh[NBUK];
    for (int i = threadIdx.x; i < NBUK; i += 256) lh[i] = 0;
    __syncthreads();
    int is64 = flag[0];
    int s = blockIdx.x * TILE, e1 = min(s + TILE, N_EDGES);
    for (int e = s + threadIdx.x; e < e1; e += 256) {
        int c = eidx(ei, is64, N_EDGES + e);
        atomicAdd(&lh[c >> 8], 1);
    }
    __syncthreads();
    for (int i = threadIdx.x; i < NBUK; i += 256)
        if (lh[i]) atomicAdd(&bcnt[i], lh[i]);
}

// scan of NBUK bucket counts -> bstart (excl, +total at [NBUK]) and bcursor
__global__ void k_bscan(const int* __restrict__ bcnt, int* __restrict__ bstart,
                        int* __restrict__ bcursor) {
    __shared__ int s[512];
    int t = threadIdx.x;
    int v = (t < NBUK) ? bcnt[t] : 0;
    s[t] = v;
    __syncthreads();
    for (int off = 1; off < 512; off <<= 1) {
        int u = (t >= off) ? s[t - off] : 0;
        __syncthreads();
        s[t] += u;
        __syncthreads();
    }
    int excl = s[t] - v;
    if (t <= NBUK) bstart[t] = excl;
    if (t < NBUK)  bcursor[t] = excl;
}

// pass A1: scatter edges into bucket-major abuf with block-reserved runs
__global__ __launch_bounds__(256)
void k_bscat(const int* __restrict__ ei, const float* __restrict__ ew,
             const int* __restrict__ flag, int* __restrict__ bcursor,
             uint2* __restrict__ abuf) {
    __shared__ int lh[NBUK];
    __shared__ int lbase[NBUK];
    __shared__ int lcur[NBUK];
    for (int i = threadIdx.x; i < NBUK; i += 256) { lh[i] = 0; lcur[i] = 0; }
    __syncthreads();
    int is64 = flag[0];
    int s = blockIdx.x * TILE, e1 = min(s + TILE, N_EDGES);
    for (int e = s + threadIdx.x; e < e1; e += 256) {
        int c = eidx(ei, is64, N_EDGES + e);
        atomicAdd(&lh[c >> 8], 1);
    }
    __syncthreads();
    for (int i = threadIdx.x; i < NBUK; i += 256)
        if (lh[i]) lbase[i] = atomicAdd(&bcursor[i], lh[i]);
    __syncthreads();
    for (int e = s + threadIdx.x; e < e1; e += 256) {
        int r = eidx(ei, is64, e);
        int c = eidx(ei, is64, N_EDGES + e);
        float w = ew[e];
        int b = c >> 8;
        int off = atomicAdd(&lcur[b], 1);
        int p = lbase[b] + off;
        abuf[p] = make_uint2((unsigned)r | ((unsigned)(c & 255) << 17),
                             __float_as_uint(w));
    }
}

// pass B: per-bucket counting sort into final CSR; emits start/counts/dinv
__global__ __launch_bounds__(256)
void k_bsort(const int* __restrict__ bstart, const uint2* __restrict__ abuf,
             int* __restrict__ rperm, float* __restrict__ wperm,
             int* __restrict__ startA, int* __restrict__ counts,
             float* __restrict__ dinv) {
    __shared__ int   cnt[256];
    __shared__ int   scn[256];
    __shared__ int   cur[256];
    __shared__ float wsum[256];
    int t = threadIdx.x;
    int b = blockIdx.x;
    int s0 = bstart[b], s1 = bstart[b + 1];
    cnt[t] = 0; wsum[t] = 0.0f;
    __syncthreads();
    for (int k = s0 + t; k < s1; k += 256) {
        int ln = (int)(abuf[k].x >> 17);
        atomicAdd(&cnt[ln], 1);
    }
    __syncthreads();
    scn[t] = cnt[t];
    __syncthreads();
    for (int off = 1; off < 256; off <<= 1) {
        int u = (t >= off) ? scn[t - off] : 0;
        __syncthreads();
        scn[t] += u;
        __syncthreads();
    }
    int excl = scn[t] - cnt[t];
    cur[t] = excl;
    int node = b * 256 + t;
    if (node < N_NODES) {
        startA[node] = s0 + excl;
        counts[node] = cnt[t];
    }
    __syncthreads();
    for (int k = s0 + t; k < s1; k += 256) {
        uint2 a = abuf[k];
        int ln = (int)(a.x >> 17);
        int r  = (int)(a.x & 0x1FFFFu);
        float w = __uint_as_float(a.y);
        int off = atomicAdd(&cur[ln], 1);
        int p = s0 + off;
        rperm[p] = r;
        wperm[p] = w;
        atomicAdd(&wsum[ln], w);
    }
    __syncthreads();
    if (node < N_NODES) dinv[node] = rsqrtf(1.0f + wsum[t]);   // deg >= 1 (self-loop)
}

// ---------- layer 1 transform: h1 = x @ W1 ----------
// Thread-per-row, 16 k-chunks of 32. x tile staged TRANSPOSED in LDS
// (xT[k][row], pad 257: write banks (4c+d+row)%32 <=2-way, read banks (k+t)%32
// conflict-free). W1 indexed uniformly -> s_load, SGPR operand folds into FMA.
// Register double-buffer hides HBM latency under the 512 FMA/chunk.

__global__ __launch_bounds__(256)
void k_gemm1(const float* __restrict__ x, const float* __restrict__ W1g,
             float* __restrict__ h1) {
    __shared__ float xT[32 * 257];          // 32.9 KB -> 4 blocks/CU
    const int t = threadIdx.x;
    const int row0 = blockIdx.x * 256;
    const int myrow = row0 + t;

    float4 rg[8], rn[8];

    // load chunk 0
#pragma unroll
    for (int p = 0; p < 8; ++p) {
        int f = t + 256 * p;
        int lr = f >> 3, lc = f & 7;
        int gr = min(row0 + lr, N_NODES - 1);
        rg[p] = *(const float4*)(x + (size_t)gr * D_FEAT + 4 * lc);
    }

    float acc[16];
#pragma unroll
    for (int j = 0; j < 16; ++j) acc[j] = 0.0f;

    for (int ch = 0; ch < 16; ++ch) {
        __syncthreads();                    // prior compute done, LDS reusable
#pragma unroll
        for (int p = 0; p < 8; ++p) {
            int f = t + 256 * p;
            int lr = f >> 3, lc = f & 7;
            xT[(4 * lc + 0) * 257 + lr] = rg[p].x;
            xT[(4 * lc + 1) * 257 + lr] = rg[p].y;
            xT[(4 * lc + 2) * 257 + lr] = rg[p].z;
            xT[(4 * lc + 3) * 257 + lr] = rg[p].w;
        }
        if (ch < 15) {
            int k0n = (ch + 1) * 32;
#pragma unroll
            for (int p = 0; p < 8; ++p) {
                int f = t + 256 * p;
                int lr = f >> 3, lc = f & 7;
                int gr = min(row0 + lr, N_NODES - 1);
                rn[p] = *(const float4*)(x + (size_t)gr * D_FEAT + k0n + 4 * lc);
            }
        }
        __syncthreads();                    // tile ready
        const int k0 = ch * 32;
#pragma unroll
        for (int k = 0; k < 32; ++k) {
            float xk = xT[k * 257 + t];
            const float* wr = W1g + ((size_t)(k0 + k) << 4);   // uniform -> s_load
#pragma unroll
            for (int j = 0; j < 16; ++j) acc[j] = fmaf(xk, wr[j], acc[j]);
        }
#pragma unroll
        for (int p = 0; p < 8; ++p) rg[p] = rn[p];
    }

    if (myrow < N_NODES) {
        float4* o = (float4*)(h1 + (size_t)myrow * HIDDEN);
        o[0] = make_float4(acc[0],  acc[1],  acc[2],  acc[3]);
        o[1] = make_float4(acc[4],  acc[5],  acc[6],  acc[7]);
        o[2] = make_float4(acc[8],  acc[9],  acc[10], acc[11]);
        o[3] = make_float4(acc[12], acc[13], acc[14], acc[15]);
    }
}

// ---------- gather layer 1 (+ bias + self-loop) fused with gemm2 ----------
// wperm holds raw w; dinv[row] applied inline (L1-resident 400KB table).

__global__ __launch_bounds__(256)
void k_gather1(const int* __restrict__ start, const int* __restrict__ counts,
               const int* __restrict__ rperm, const float* __restrict__ wperm,
               const float* __restrict__ dinv, const float* __restrict__ h1,
               const float* __restrict__ b1, const float* __restrict__ W2g,
               float* __restrict__ x1, float* __restrict__ h2) {
    __shared__ float sW2[HIDDEN * NCLS];
    __shared__ float sv[16][HIDDEN + 1];
    if (threadIdx.x < HIDDEN * NCLS) sW2[threadIdx.x] = W2g[threadIdx.x];
    int ln = threadIdx.x >> 4, j = threadIdx.x & 15;
    int i = blockIdx.x * 16 + ln;
    bool act = (i < N_NODES);
    float v = 0.0f;
    if (act) {
        int s0 = start[i], n = counts[i];
        float acc = 0.0f;
        for (int k = 0; k < n; ++k) {
            int r = rperm[s0 + k];
            acc += wperm[s0 + k] * dinv[r] * h1[(size_t)r * HIDDEN + j];
        }
        float di = dinv[i];
        v = di * acc + di * di * h1[(size_t)i * HIDDEN + j] + b1[j];
        x1[(size_t)i * HIDDEN + j] = v;
    }
    sv[ln][j] = v;
    __syncthreads();
    if (act && j < NCLS) {
        float a = 0.0f;
#pragma unroll
        for (int k = 0; k < HIDDEN; ++k) a = fmaf(sv[ln][k], sW2[k * NCLS + j], a);
        h2[(size_t)i * NCLS + j] = a;
    }
}

// ---------- gather layer 2 fused with log_softmax ----------

__global__ __launch_bounds__(256)
void k_gather2(const int* __restrict__ start, const int* __restrict__ counts,
               const int* __restrict__ rperm, const float* __restrict__ wperm,
               const float* __restrict__ dinv, const float* __restrict__ h2,
               const float* __restrict__ b2, float* __restrict__ out) {
    __shared__ float sv[32][8];
    int ln = threadIdx.x >> 3, j = threadIdx.x & 7;
    int i = blockIdx.x * 32 + ln;
    bool act = (i < N_NODES) && (j < NCLS);
    float v = 0.0f;
    if (act) {
        int s0 = start[i], n = counts[i];
        float acc = 0.0f;
        for (int k = 0; k < n; ++k) {
            int r = rperm[s0 + k];
            acc += wperm[s0 + k] * dinv[r] * h2[(size_t)r * NCLS + j];
        }
        float di = dinv[i];
        v = di * acc + di * di * h2[(size_t)i * NCLS + j] + b2[j];
    }
    sv[ln][j] = v;
    __syncthreads();
    if (act) {
        float m = -1e30f;
#pragma unroll
        for (int k = 0; k < NCLS; ++k) m = fmaxf(m, sv[ln][k]);
        float s = 0.0f;
#pragma unroll
        for (int k = 0; k < NCLS; ++k) s += __expf(sv[ln][k] - m);
        out[(size_t)i * NCLS + j] = v - m - __logf(s);
    }
}

// ---------- tier-2 CSR build kernels (R2 path, proven) ----------

__global__ void k_hist(const int* __restrict__ ei, const int* __restrict__ flag,
                       int* __restrict__ counts) {
    int e = blockIdx.x * 256 + threadIdx.x;
    if (e >= N_EDGES) return;
    int c = eidx(ei, flag[0], N_EDGES + e);
    atomicAdd(&counts[c], 1);
}

__global__ void k_scanA(const int* __restrict__ counts, int* __restrict__ excl,
                        int* __restrict__ bsum) {
    __shared__ int s[256];
    int t = threadIdx.x;
    int i = blockIdx.x * 256 + t;
    int v = (i < N_NODES) ? counts[i] : 0;
    s[t] = v;
    __syncthreads();
    for (int off = 1; off < 256; off <<= 1) {
        int u = (t >= off) ? s[t - off] : 0;
        __syncthreads();
        s[t] += u;
        __syncthreads();
    }
    if (i < N_NODES) excl[i] = s[t] - v;
    if (t == 255) bsum[blockIdx.x] = s[255];
}

__global__ void k_scanB(int* __restrict__ bsum, int nb) {
    __shared__ int s[512];
    int t = threadIdx.x;
    int v = (t < nb) ? bsum[t] : 0;
    s[t] = v;
    __syncthreads();
    for (int off = 1; off < 512; off <<= 1) {
        int u = (t >= off) ? s[t - off] : 0;
        __syncthreads();
        s[t] += u;
        __syncthreads();
    }
    if (t < nb) bsum[t] = s[t] - v;
}

__global__ void k_scanC(int* __restrict__ excl, const int* __restrict__ bsum) {
    int i = blockIdx.x * 256 + threadIdx.x;
    if (i < N_NODES) excl[i] += bsum[blockIdx.x];
}

__global__ void k_fill(const int* __restrict__ ei, const float* __restrict__ ew,
                       const int* __restrict__ flag, const int* __restrict__ start,
                       int* __restrict__ cursor, int* __restrict__ rperm,
                       float* __restrict__ wperm) {
    int e = blockIdx.x * 256 + threadIdx.x;
    if (e >= N_EDGES) return;
    int is64 = flag[0];
    int r = eidx(ei, is64, e);
    int c = eidx(ei, is64, N_EDGES + e);
    int p = start[c] + atomicAdd(&cursor[c], 1);
    rperm[p] = r;
    wperm[p] = ew[e];
}

__global__ void k_deg(const int* __restrict__ start, const int* __restrict__ counts,
                      const float* __restrict__ wperm, float* __restrict__ deg) {
    int i = blockIdx.x * 256 + threadIdx.x;
    if (i >= N_NODES) return;
    int s0 = start[i], n = counts[i];
    float s = 1.0f;
    for (int k = 0; k < n; ++k) s += wperm[s0 + k];
    deg[i] = rsqrtf(s);
}

// ---------- tier-3 atomic fallback kernels ----------

__global__ void k_initdeg(float* __restrict__ deg) {
    int i = blockIdx.x * 256 + threadIdx.x;
    if (i < N_NODES) deg[i] = 1.0f;
}

__global__ void k_degacc(const int* __restrict__ ei, const float* __restrict__ w,
                         const int* __restrict__ flag, float* __restrict__ deg) {
    int e = blockIdx.x * 256 + threadIdx.x;
    if (e >= N_EDGES) return;
    int c = eidx(ei, flag[0], N_EDGES + e);
    atomicAdd(&deg[c], w[e]);
}

__global__ void k_dinv(float* __restrict__ deg) {
    int i = blockIdx.x * 256 + threadIdx.x;
    if (i < N_NODES) {
        float d = deg[i];
        deg[i] = (d > 0.0f) ? rsqrtf(d) : 0.0f;
    }
}

__global__ __launch_bounds__(256)
void k_scatter1(const int* __restrict__ ei, const float* __restrict__ w,
                const int* __restrict__ flag, const float* __restrict__ dinv,
                const float* __restrict__ h1, float* __restrict__ agg1) {
    int t = blockIdx.x * 256 + threadIdx.x;
    if (t >= N_EDGES * HIDDEN) return;
    int e = t >> 4, j = t & 15;
    int is64 = flag[0];
    int r = eidx(ei, is64, e);
    int c = eidx(ei, is64, N_EDGES + e);
    float nrm = dinv[r] * w[e] * dinv[c];
    atomicAdd(&agg1[(size_t)c * HIDDEN + j], nrm * h1[(size_t)r * HIDDEN + j]);
}

__global__ void k_fin1_gemm2(const float* __restrict__ b1, const float* __restrict__ W2,
                             const float* __restrict__ dinv, const float* __restrict__ h1,
                             float* __restrict__ x1, float* __restrict__ h2) {
    int i = blockIdx.x * 256 + threadIdx.x;
    if (i >= N_NODES) return;
    float d2 = dinv[i] * dinv[i];
    float v[HIDDEN];
#pragma unroll
    for (int k = 0; k < HIDDEN; ++k)
        v[k] = x1[(size_t)i * HIDDEN + k] + d2 * h1[(size_t)i * HIDDEN + k] + b1[k];
#pragma unroll
    for (int k = 0; k < HIDDEN; ++k)
        x1[(size_t)i * HIDDEN + k] = v[k];
#pragma unroll
    for (int j = 0; j < NCLS; ++j) {
        float a = 0.0f;
#pragma unroll
        for (int k = 0; k < HIDDEN; ++k) a = fmaf(v[k], W2[k * NCLS + j], a);
        h2[(size_t)i * NCLS + j] = a;
    }
}

__global__ __launch_bounds__(256)
void k_scatter2(const int* __restrict__ ei, const float* __restrict__ w,
                const int* __restrict__ flag, const float* __restrict__ dinv,
                const float* __restrict__ h2, float* __restrict__ agg2) {
    int t = blockIdx.x * 256 + threadIdx.x;
    if (t >= N_EDGES * NCLS) return;
    int e = t / NCLS, j = t - e * NCLS;
    int is64 = flag[0];
    int r = eidx(ei, is64, e);
    int c = eidx(ei, is64, N_EDGES + e);
    float nrm = dinv[r] * w[e] * dinv[c];
    atomicAdd(&agg2[(size_t)c * NCLS + j], nrm * h2[(size_t)r * NCLS + j]);
}

__global__ void k_final(const float* __restrict__ agg2, const float* __restrict__ h2,
                        const float* __restrict__ dinv, const float* __restrict__ b2,
                        float* __restrict__ out) {
    int i = blockIdx.x * 256 + threadIdx.x;
    if (i >= N_NODES) return;
    float d2 = dinv[i] * dinv[i];
    float v[NCLS];
    float m = -1e30f;
#pragma unroll
    for (int j = 0; j < NCLS; ++j) {
        v[j] = agg2[(size_t)i * NCLS + j] + d2 * h2[(size_t)i * NCLS + j] + b2[j];
        m = fmaxf(m, v[j]);
    }
    float s = 0.0f;
#pragma unroll
    for (int j = 0; j < NCLS; ++j) s += __expf(v[j] - m);
    float l = __logf(s);
#pragma unroll
    for (int j = 0; j < NCLS; ++j) out[(size_t)i * NCLS + j] = v[j] - m - l;
}

// ---------- launch ----------

extern "C" void kernel_launch(void* const* d_in, const int* in_sizes, int n_in,
                              void* d_out, int out_size, void* d_ws, size_t ws_size,
                              hipStream_t stream) {
    const float* x  = (const float*)d_in[0];
    const float* W1 = (const float*)d_in[1];
    const float* b1 = (const float*)d_in[2];
    const float* W2 = (const float*)d_in[3];
    const float* b2 = (const float*)d_in[4];
    const float* ew = (const float*)d_in[5];
    const int*   ei = (const int*)d_in[6];

    float* out = (float*)d_out;
    float* lsm = out;                               // [N, 6]
    float* x1  = out + (size_t)N_NODES * NCLS;      // [N, 16]

    const int NB_N = (N_NODES + 255) / 256;         // 391
    const int NB_E = (N_EDGES + 255) / 256;

    float* W    = (float*)d_ws;
    int*   flag = (int*)d_ws;

    // ---- tier-1 radix layout (4B words) ----
    int*   bcnt    = (int*)(W + 256);        // 392
    int*   bstart  = (int*)(W + 768);        // 392
    int*   bcursor = (int*)(W + 1280);       // 391
    int*   countsR = (int*)(W + 1792);       // 100000
    int*   startR  = (int*)(W + 102400);     // 100001
    float* dinvR   = W + 202496;             // 100000
    uint2* abuf    = (uint2*)(W + 302848);   // 3.2M uint2 (25.6MB), aliased with:
    float* h1R     = W + 302848;             //   1.6M (written after abuf dies)
    float* h2R     = W + 1902848;            //   600K
    int*   rpermR  = (int*)(W + 6702848);    // 3.2M
    float* wpermR  = W + 9902848;            // 3.2M
    const size_t NEED2 = (size_t)13102848 * 4;      // ~52.4 MB

    // ---- tier-2 (R2) layout ----
    float* deg    = W + 1024;
    int*   counts = (int*)(W + 102400);
    int*   startA = (int*)(W + 203776);
    int*   cursor = (int*)(W + 304128);
    int*   bsum   = (int*)(W + 405504);
    float* h1     = W + 406528;
    float* h2     = W + 2007040;
    int*   rperm  = (int*)(W + 2607616);
    float* wperm  = W + 5808128;
    const size_t NEED1 = (size_t)9008128 * 4;       // ~36 MB

    if (ws_size >= NEED2) {
        hipMemsetAsync(bcnt, 0, 392 * 4, stream);
        k_detect<<<1, 64, 0, stream>>>(ei, flag);
        k_bhist <<<NBLK_A, 256, 0, stream>>>(ei, flag, bcnt);
        k_bscan <<<1, 512, 0, stream>>>(bcnt, bstart, bcursor);
        k_bscat <<<NBLK_A, 256, 0, stream>>>(ei, ew, flag, bcursor, abuf);
        k_bsort <<<NBUK, 256, 0, stream>>>(bstart, abuf, rpermR, wpermR,
                                           startR, countsR, dinvR);
        k_gemm1 <<<NB_N, 256, 0, stream>>>(x, W1, h1R);
        k_gather1<<<(N_NODES + 15) / 16, 256, 0, stream>>>(startR, countsR, rpermR, wpermR,
                                                           dinvR, h1R, b1, W2, x1, h2R);
        k_gather2<<<(N_NODES + 31) / 32, 256, 0, stream>>>(startR, countsR, rpermR, wpermR,
                                                           dinvR, h2R, b2, lsm);
    } else if (ws_size >= NEED1) {
        hipMemsetAsync(counts, 0, (size_t)N_NODES * 4, stream);
        hipMemsetAsync(cursor, 0, (size_t)N_NODES * 4, stream);
        k_detect<<<1, 64, 0, stream>>>(ei, flag);
        k_hist  <<<NB_E, 256, 0, stream>>>(ei, flag, counts);
        k_scanA <<<NB_N, 256, 0, stream>>>(counts, startA, bsum);
        k_scanB <<<1, 512, 0, stream>>>(bsum, NB_N);
        k_scanC <<<NB_N, 256, 0, stream>>>(startA, bsum);
        k_fill  <<<NB_E, 256, 0, stream>>>(ei, ew, flag, startA, cursor, rperm, wperm);
        k_deg   <<<NB_N, 256, 0, stream>>>(startA, counts, wperm, deg);
        k_gemm1 <<<NB_N, 256, 0, stream>>>(x, W1, h1);
        k_gather1<<<(N_NODES + 15) / 16, 256, 0, stream>>>(startA, counts, rperm, wperm,
                                                           deg, h1, b1, W2, x1, h2);
        k_gather2<<<(N_NODES + 31) / 32, 256, 0, stream>>>(startA, counts, rperm, wperm,
                                                           deg, h2, b2, lsm);
    } else {
        float* fh1  = W + 101376;
        float* fh2  = fh1 + (size_t)N_NODES * HIDDEN;
        float* agg2 = fh2 + (size_t)N_NODES * NCLS;
        hipMemsetAsync(x1,   0, (size_t)N_NODES * HIDDEN * sizeof(float), stream);
        hipMemsetAsync(agg2, 0, (size_t)N_NODES * NCLS   * sizeof(float), stream);
        k_detect <<<1, 64, 0, stream>>>(ei, flag);
        k_initdeg<<<NB_N, 256, 0, stream>>>(deg);
        k_degacc <<<NB_E, 256, 0, stream>>>(ei, ew, flag, deg);
        k_dinv   <<<NB_N, 256, 0, stream>>>(deg);
        k_gemm1  <<<NB_N, 256, 0, stream>>>(x, W1, fh1);
        k_scatter1<<<(N_EDGES * HIDDEN + 255) / 256, 256, 0, stream>>>(ei, ew, flag, deg, fh1, x1);
        k_fin1_gemm2<<<NB_N, 256, 0, stream>>>(b1, W2, deg, fh1, x1, fh2);
        k_scatter2<<<(N_EDGES * NCLS + 255) / 256, 256, 0, stream>>>(ei, ew, flag, deg, fh2, agg2);
        k_final  <<<NB_N, 256, 0, stream>>>(agg2, fh2, deg, b2, lsm);
    }
}